// Round 6
// baseline (336.440 us; speedup 1.0000x reference)
//
#include <hip/hip_runtime.h>
#include <hip/hip_bf16.h>
#include <math.h>

// CausalSelfAttention: B=4, S=2048, D=1024, H=16, HD=64
// v6: attention with double-buffered LDS K/V staging via global_load_lds
//     (prefetch-ahead pipeline: barrier drains loads issued a full stage
//     earlier), balanced q-assignment (all waves share causal range),
//     native exp2, V transposed in GEMM1 epilogue.

typedef __bf16 bf16;
typedef __bf16 bf16x8 __attribute__((ext_vector_type(8)));
typedef __bf16 bf16x4 __attribute__((ext_vector_type(4)));
typedef float f32x4 __attribute__((ext_vector_type(4)));

#define B_ 4
#define S_ 2048
#define D_ 1024
#define H_ 16
#define HD_ 64
#define QSCALE 0.1803368801f  /* 0.125 * log2(e) */

#if __has_builtin(__builtin_amdgcn_exp2f)
#define EXP2F(x) __builtin_amdgcn_exp2f(x)
#else
#define EXP2F(x) exp2f(x)
#endif
#if __has_builtin(__builtin_amdgcn_rcpf)
#define RCPF(x) __builtin_amdgcn_rcpf(x)
#else
#define RCPF(x) (1.0f / (x))
#endif

#define GLOAD_LDS16(gptr, lptr)                                              \
    __builtin_amdgcn_global_load_lds(                                        \
        (const __attribute__((address_space(1))) void*)(uintptr_t)(gptr),    \
        (__attribute__((address_space(3))) void*)(uintptr_t)(lptr), 16, 0, 0)

template <int CTRL>
__device__ __forceinline__ float dpp_mov_f(float x) {
    int xi = __builtin_bit_cast(int, x);
    int r = __builtin_amdgcn_mov_dpp(xi, CTRL, 0xF, 0xF, true);
    return __builtin_bit_cast(float, r);
}
// sum over the 16-lane DPP row
__device__ __forceinline__ float rowsum16(float x) {
    x += dpp_mov_f<0xB1>(x);
    x += dpp_mov_f<0x4E>(x);
    x += dpp_mov_f<0x124>(x);
    x += dpp_mov_f<0x128>(x);
    return x;
}

// ---------------- convert fp32 -> bf16 ----------------
__global__ void k_cvt(const float* __restrict__ in, bf16* __restrict__ out, int n) {
    int i = (blockIdx.x * 256 + threadIdx.x) * 4;
    if (i >= n) return;
    float4 v = *reinterpret_cast<const float4*>(in + i);
    bf16x4 o;
    o.x = (bf16)v.x; o.y = (bf16)v.y; o.z = (bf16)v.z; o.w = (bf16)v.w;
    *reinterpret_cast<bf16x4*>(out + i) = o;
}

// ---------------- transpose + convert: W[K][N] -> WT[N][K] bf16 ----------------
__global__ void k_transpose_cvt(const float* __restrict__ W, bf16* __restrict__ WT,
                                int K, int N) {
    __shared__ float t[32][33];
    int n0 = blockIdx.x * 32, k0 = blockIdx.y * 32;
    int tx = threadIdx.x & 31, ty = threadIdx.x >> 5;
#pragma unroll
    for (int j = 0; j < 32; j += 8)
        t[ty + j][tx] = W[(size_t)(k0 + ty + j) * N + n0 + tx];
    __syncthreads();
#pragma unroll
    for (int j = 0; j < 32; j += 8)
        WT[(size_t)(n0 + ty + j) * K + k0 + tx] = (bf16)t[tx][ty + j];
}

// ---------------- bf16 MFMA GEMM (m97-style): C = A[M][K] * BT[N][K]^T ---------
// MODE 0: Q (prescaled) [bh][s][d], K [bh][s][d], V -> Vt [bh][d][s] (packed 8B)
// MODE 1: fp32 out[M][N]
template <int MODE>
__global__ __launch_bounds__(256) void k_gemm(
    const bf16* __restrict__ A, const bf16* __restrict__ BT,
    const float* __restrict__ bias,
    void* out0, void* out1, void* out2, int M, int N, int K) {
    __shared__ __align__(16) bf16 Asm[128 * 32];
    __shared__ __align__(16) bf16 Bsm[128 * 32];
    int mb = blockIdx.y * 128, nb = blockIdx.x * 128;
    int tid = threadIdx.x;
    int w = tid >> 6, lane = tid & 63, lo = lane & 15, qu = lane >> 4;
    int wm = (w >> 1) * 64, wn = (w & 1) * 64;
    int srow_in_wave = lane >> 2;
    int schunk = lane & 3;
    f32x4 zero = {0.f, 0.f, 0.f, 0.f};
    f32x4 acc[4][4];
#pragma unroll
    for (int i = 0; i < 4; i++)
#pragma unroll
        for (int j = 0; j < 4; j++) acc[i][j] = zero;

    int fswz = (lo >> 1) & 3;

    for (int kb = 0; kb < K; kb += 32) {
        __syncthreads();
#pragma unroll
        for (int u = 0; u < 2; u++) {
            int row0 = w * 32 + u * 16;
            int row = row0 + srow_in_wave;
            int cg = schunk ^ ((row >> 1) & 3);
            GLOAD_LDS16(A + (size_t)(mb + row) * K + kb + cg * 8, &Asm[row0 * 32]);
            GLOAD_LDS16(BT + (size_t)(nb + row) * K + kb + cg * 8, &Bsm[row0 * 32]);
        }
        __syncthreads();
        bf16x8 af[4], bfr[4];
#pragma unroll
        for (int t = 0; t < 4; t++) {
            af[t]  = *reinterpret_cast<const bf16x8*>(
                &Asm[(wm + t * 16 + lo) * 32 + (qu ^ fswz) * 8]);
            bfr[t] = *reinterpret_cast<const bf16x8*>(
                &Bsm[(wn + t * 16 + lo) * 32 + (qu ^ fswz) * 8]);
        }
#pragma unroll
        for (int i = 0; i < 4; i++)
#pragma unroll
            for (int j = 0; j < 4; j++)
                acc[i][j] = __builtin_amdgcn_mfma_f32_16x16x32_bf16(af[i], bfr[j],
                                                                    acc[i][j], 0, 0, 0);
    }
#pragma unroll
    for (int i = 0; i < 4; i++) {
#pragma unroll
        for (int j = 0; j < 4; j++) {
            int col = nb + wn + j * 16 + lo;
            float bv = bias[col];
            float v4v[4];
#pragma unroll
            for (int r = 0; r < 4; r++) v4v[r] = acc[i][j][r] + bv;
            int row0 = mb + wm + i * 16 + qu * 4;
            if (MODE == 0) {
                int b = row0 >> 11, s0 = row0 & 2047;
                int which = col >> 10, rem = col & 1023;
                int h = rem >> 6, d = rem & 63;
                int bh = b * H_ + h;
                if (which == 2) {
                    bf16x4 pk;
#pragma unroll
                    for (int r = 0; r < 4; r++) pk[r] = (bf16)v4v[r];
                    *reinterpret_cast<bf16x4*>(
                        (bf16*)out2 + ((size_t)bh * HD_ + d) * S_ + s0) = pk;
                } else {
                    bf16* dst = which == 0 ? (bf16*)out0 : (bf16*)out1;
                    float sc = which == 0 ? QSCALE : 1.0f;
#pragma unroll
                    for (int r = 0; r < 4; r++)
                        dst[((size_t)bh * S_ + s0 + r) * HD_ + d] = (bf16)(v4v[r] * sc);
                }
            } else {
#pragma unroll
                for (int r = 0; r < 4; r++)
                    ((float*)out0)[(size_t)(row0 + r) * N + col] = v4v[r];
            }
        }
    }
}

// ---------------- flash attention v6: LDS double-buffer pipeline ----------------
// grid (16, 64): block = (bh, 128 q), 4 waves. Wave w owns q-rows
// {qt*128 + w*16} and {qt*128 + 64 + w*16} (balanced causal range).
// K/V staged via global_load_lds (slot = chunk ^ (row&7)), double-buffered:
// barrier at stage t drains prefetch issued at t-1. One barrier per stage.
__global__ __launch_bounds__(256) void k_attn(
    const bf16* __restrict__ Q, const bf16* __restrict__ K,
    const bf16* __restrict__ Vt, bf16* __restrict__ Y) {
    __shared__ __align__(16) bf16 Kbuf[2 * 64 * 64];   // [buf][key][d] swizzled
    __shared__ __align__(16) bf16 Vbuf[2 * 64 * 64];   // [buf][d][key] swizzled
    __shared__ __align__(16) bf16 Psm[4][32][72];      // per-wave [q][key]
    int qt = 15 - (int)blockIdx.x;  // long blocks first
    int bh = blockIdx.y;
    int b = bh >> 4, h = bh & 15;
    int tid = threadIdx.x, w = tid >> 6, lane = tid & 63;
    int lo = lane & 15, qu = lane >> 4, lo7 = lo & 7;
    const bf16* Qb = Q + (size_t)bh * S_ * HD_;
    const bf16* Kb = K + (size_t)bh * S_ * HD_;
    const bf16* Vb = Vt + (size_t)bh * HD_ * S_;

    int qrow[2] = {qt * 128 + w * 16, qt * 128 + 64 + w * 16};

    // Q fragments (A layout: m=lo, k=qu*8+j, +32*ks)
    bf16x8 qf[2][2];
#pragma unroll
    for (int i = 0; i < 2; i++)
#pragma unroll
        for (int ks = 0; ks < 2; ks++)
            qf[i][ks] = *reinterpret_cast<const bf16x8*>(
                Qb + (size_t)(qrow[i] + lo) * HD_ + ks * 32 + qu * 8);

    f32x4 zero = {0.f, 0.f, 0.f, 0.f};
    f32x4 o[2][4];
    float l_i[2][4];
#pragma unroll
    for (int i = 0; i < 2; i++)
#pragma unroll
        for (int r = 0; r < 4; r++) { o[i][r] = zero; l_i[i][r] = 0.f; }

    // staging lane constants: lane -> local row lane>>3 (0..7), slot lane&7,
    // global chunk = slot ^ localrow  (row base multiple of 8)
    int srow = lane >> 3;
    int scg = (lane & 7) ^ srow;
    // wave w stages rows w*16..w*16+15 (two instrs of 8 rows)
    const bf16* Kg0 = Kb + (size_t)(w * 16 + 0 + srow) * HD_ + scg * 8;
    const bf16* Kg1 = Kb + (size_t)(w * 16 + 8 + srow) * HD_ + scg * 8;
    const bf16* Vg0 = Vb + (size_t)(w * 16 + 0 + srow) * S_ + scg * 8;
    const bf16* Vg1 = Vb + (size_t)(w * 16 + 8 + srow) * S_ + scg * 8;

    int ntb = 2 * qt + 2;
    // prologue: stage tile 0 into buf 0
    GLOAD_LDS16(Kg0, &Kbuf[(w * 16 + 0) * 64]);
    GLOAD_LDS16(Kg1, &Kbuf[(w * 16 + 8) * 64]);
    GLOAD_LDS16(Vg0, &Vbuf[(w * 16 + 0) * 64]);
    GLOAD_LDS16(Vg1, &Vbuf[(w * 16 + 8) * 64]);

    for (int t = 0; t < ntb; t++) {
        int kb = t * 64;
        __syncthreads();  // drains prefetch issued last stage (or prologue)
        if (t + 1 < ntb) {
            int nb = ((t + 1) & 1) * 64 * 64;
            size_t koff = (size_t)(kb + 64) * HD_;
            GLOAD_LDS16(Kg0 + koff, &Kbuf[nb + (w * 16 + 0) * 64]);
            GLOAD_LDS16(Kg1 + koff, &Kbuf[nb + (w * 16 + 8) * 64]);
            GLOAD_LDS16(Vg0 + kb + 64, &Vbuf[nb + (w * 16 + 0) * 64]);
            GLOAD_LDS16(Vg1 + kb + 64, &Vbuf[nb + (w * 16 + 8) * 64]);
        }
        const bf16* Kt = &Kbuf[(t & 1) * 64 * 64];
        const bf16* Vtl = &Vbuf[(t & 1) * 64 * 64];
        bool act[2] = {kb <= qrow[0] + 15, kb <= qrow[1] + 15};

        // ---- S = Q K^T ----
        f32x4 sc[2][4];
#pragma unroll
        for (int kc = 0; kc < 4; kc++) {
            bf16x8 k0 = *reinterpret_cast<const bf16x8*>(
                &Kt[(kc * 16 + lo) * 64 + ((qu ^ lo7) * 8)]);
            bf16x8 k1 = *reinterpret_cast<const bf16x8*>(
                &Kt[(kc * 16 + lo) * 64 + (((4 + qu) ^ lo7) * 8)]);
#pragma unroll
            for (int i = 0; i < 2; i++)
                if (act[i]) {
                    f32x4 a = __builtin_amdgcn_mfma_f32_16x16x32_bf16(qf[i][0], k0, zero, 0, 0, 0);
                    sc[i][kc] = __builtin_amdgcn_mfma_f32_16x16x32_bf16(qf[i][1], k1, a, 0, 0, 0);
                }
        }
        // ---- mask (partial tiles) + exp2 + row-sum ----
#pragma unroll
        for (int i = 0; i < 2; i++) {
            if (!act[i]) continue;
            if (kb + 63 > qrow[i]) {
#pragma unroll
                for (int kc = 0; kc < 4; kc++) {
                    int kj = kb + kc * 16 + lo;
                    int qi = qrow[i] + qu * 4;
#pragma unroll
                    for (int r = 0; r < 4; r++)
                        sc[i][kc][r] = (kj > qi + r) ? -1e30f : sc[i][kc][r];
                }
            }
#pragma unroll
            for (int kc = 0; kc < 4; kc++)
#pragma unroll
                for (int r = 0; r < 4; r++)
                    sc[i][kc][r] = EXP2F(sc[i][kc][r]);
#pragma unroll
            for (int r = 0; r < 4; r++) {
                float s = (sc[i][0][r] + sc[i][1][r]) + (sc[i][2][r] + sc[i][3][r]);
                l_i[i][r] += rowsum16(s);
            }
            // P: C layout -> per-wave LDS
#pragma unroll
            for (int kc = 0; kc < 4; kc++)
#pragma unroll
                for (int r = 0; r < 4; r++)
                    Psm[w][i * 16 + qu * 4 + r][kc * 16 + lo] = (bf16)sc[i][kc][r];
        }
        asm volatile("s_waitcnt lgkmcnt(0)" ::: "memory");
        bf16x8 pa[2][2];
#pragma unroll
        for (int i = 0; i < 2; i++)
            if (act[i])
#pragma unroll
                for (int ks = 0; ks < 2; ks++)
                    pa[i][ks] = *reinterpret_cast<const bf16x8*>(
                        &Psm[w][i * 16 + lo][ks * 32 + qu * 8]);
        // ---- O += P V ----
#pragma unroll
        for (int nc = 0; nc < 4; nc++) {
            bf16x8 v0 = *reinterpret_cast<const bf16x8*>(
                &Vtl[(nc * 16 + lo) * 64 + ((qu ^ lo7) * 8)]);
            bf16x8 v1 = *reinterpret_cast<const bf16x8*>(
                &Vtl[(nc * 16 + lo) * 64 + (((4 + qu) ^ lo7) * 8)]);
#pragma unroll
            for (int i = 0; i < 2; i++)
                if (act[i]) {
                    o[i][nc] = __builtin_amdgcn_mfma_f32_16x16x32_bf16(pa[i][0], v0, o[i][nc], 0, 0, 0);
                    o[i][nc] = __builtin_amdgcn_mfma_f32_16x16x32_bf16(pa[i][1], v1, o[i][nc], 0, 0, 0);
                }
        }
    }
    // epilogue: Y[b, s, h*64 + d] bf16
#pragma unroll
    for (int i = 0; i < 2; i++) {
#pragma unroll
        for (int r = 0; r < 4; r++) {
            float inv = RCPF(l_i[i][r]);
            int s = qrow[i] + qu * 4 + r;
#pragma unroll
            for (int nc = 0; nc < 4; nc++) {
                float v = o[i][nc][r] * inv;
                Y[((size_t)(b * S_ + s) * H_ + h) * HD_ + nc * 16 + lo] = (bf16)v;
            }
        }
    }
}

extern "C" void kernel_launch(void* const* d_in, const int* in_sizes, int n_in,
                              void* d_out, int out_size, void* d_ws, size_t ws_size,
                              hipStream_t stream) {
    const float* x      = (const float*)d_in[0];
    const float* W_attn = (const float*)d_in[1];
    const float* b_attn = (const float*)d_in[2];
    const float* W_proj = (const float*)d_in[3];
    const float* b_proj = (const float*)d_in[4];
    float* out = (float*)d_out;

    char* ws = (char*)d_ws;
    size_t off = 0;
    auto alloc = [&](size_t bytes) -> void* {
        void* p = ws + off;
        off += (bytes + 255) & ~(size_t)255;
        return p;
    };
    const size_t MD = (size_t)B_ * S_ * D_;  // 8388608
    bf16* xb  = (bf16*)alloc(MD * 2);
    bf16* wta = (bf16*)alloc((size_t)3 * D_ * D_ * 2);
    bf16* wtp = (bf16*)alloc((size_t)D_ * D_ * 2);
    bf16* Qb  = (bf16*)alloc(MD * 2);
    bf16* Kb  = (bf16*)alloc(MD * 2);
    bf16* Vtb = (bf16*)alloc(MD * 2);  // V written transposed by GEMM1
    bf16* Ya  = (bf16*)alloc(MD * 2);

    k_cvt<<<8192, 256, 0, stream>>>(x, xb, (int)MD);
    k_transpose_cvt<<<dim3(96, 32), 256, 0, stream>>>(W_attn, wta, D_, 3 * D_);
    k_transpose_cvt<<<dim3(32, 32), 256, 0, stream>>>(W_proj, wtp, D_, D_);
    k_gemm<0><<<dim3(24, 64), 256, 0, stream>>>(xb, wta, b_attn, Qb, Kb, Vtb,
                                                B_ * S_, 3 * D_, D_);
    k_attn<<<dim3(16, 64), 256, 0, stream>>>(Qb, Kb, Vtb, Ya);
    k_gemm<1><<<dim3(8, 64), 256, 0, stream>>>(Ya, wtp, b_proj, out, nullptr, nullptr,
                                               B_ * S_, D_, D_);
}

// Round 7
// 328.658 us; speedup vs baseline: 1.0237x; 1.0237x over previous
//
#include <hip/hip_runtime.h>
#include <hip/hip_bf16.h>
#include <math.h>

// CausalSelfAttention: B=4, S=2048, D=1024, H=16, HD=64
// v7: v4's barrier-free attention (best occupancy) + native exp2 (v5's VALU
//     fix) WITHOUT the VGPR-costly register prefetch, + SIMD-balanced
//     q-chunk mapping (each CU's 4 blocks sum to equal work).

typedef __bf16 bf16;
typedef __bf16 bf16x8 __attribute__((ext_vector_type(8)));
typedef __bf16 bf16x4 __attribute__((ext_vector_type(4)));
typedef float f32x4 __attribute__((ext_vector_type(4)));

#define B_ 4
#define S_ 2048
#define D_ 1024
#define H_ 16
#define HD_ 64
#define QSCALE 0.1803368801f  /* 0.125 * log2(e) */

#if __has_builtin(__builtin_amdgcn_exp2f)
#define EXP2F(x) __builtin_amdgcn_exp2f(x)
#else
#define EXP2F(x) exp2f(x)
#endif
#if __has_builtin(__builtin_amdgcn_rcpf)
#define RCPF(x) __builtin_amdgcn_rcpf(x)
#else
#define RCPF(x) (1.0f / (x))
#endif

#define GLOAD_LDS16(gptr, lptr)                                              \
    __builtin_amdgcn_global_load_lds(                                        \
        (const __attribute__((address_space(1))) void*)(uintptr_t)(gptr),    \
        (__attribute__((address_space(3))) void*)(uintptr_t)(lptr), 16, 0, 0)

template <int CTRL>
__device__ __forceinline__ float dpp_mov_f(float x) {
    int xi = __builtin_bit_cast(int, x);
    int r = __builtin_amdgcn_mov_dpp(xi, CTRL, 0xF, 0xF, true);
    return __builtin_bit_cast(float, r);
}
// sum over the 16-lane DPP row
__device__ __forceinline__ float rowsum16(float x) {
    x += dpp_mov_f<0xB1>(x);
    x += dpp_mov_f<0x4E>(x);
    x += dpp_mov_f<0x124>(x);
    x += dpp_mov_f<0x128>(x);
    return x;
}

// ---------------- convert fp32 -> bf16 ----------------
__global__ void k_cvt(const float* __restrict__ in, bf16* __restrict__ out, int n) {
    int i = (blockIdx.x * 256 + threadIdx.x) * 4;
    if (i >= n) return;
    float4 v = *reinterpret_cast<const float4*>(in + i);
    bf16x4 o;
    o.x = (bf16)v.x; o.y = (bf16)v.y; o.z = (bf16)v.z; o.w = (bf16)v.w;
    *reinterpret_cast<bf16x4*>(out + i) = o;
}

// ---------------- transpose + convert: W[K][N] -> WT[N][K] bf16 ----------------
__global__ void k_transpose_cvt(const float* __restrict__ W, bf16* __restrict__ WT,
                                int K, int N) {
    __shared__ float t[32][33];
    int n0 = blockIdx.x * 32, k0 = blockIdx.y * 32;
    int tx = threadIdx.x & 31, ty = threadIdx.x >> 5;
#pragma unroll
    for (int j = 0; j < 32; j += 8)
        t[ty + j][tx] = W[(size_t)(k0 + ty + j) * N + n0 + tx];
    __syncthreads();
#pragma unroll
    for (int j = 0; j < 32; j += 8)
        WT[(size_t)(n0 + ty + j) * K + k0 + tx] = (bf16)t[tx][ty + j];
}

// ---------------- bf16 MFMA GEMM (m97-style): C = A[M][K] * BT[N][K]^T ---------
// MODE 0: Q (prescaled) [bh][s][d], K [bh][s][d], V -> Vt [bh][d][s] (packed 8B)
// MODE 1: fp32 out[M][N]
template <int MODE>
__global__ __launch_bounds__(256) void k_gemm(
    const bf16* __restrict__ A, const bf16* __restrict__ BT,
    const float* __restrict__ bias,
    void* out0, void* out1, void* out2, int M, int N, int K) {
    __shared__ __align__(16) bf16 Asm[128 * 32];
    __shared__ __align__(16) bf16 Bsm[128 * 32];
    int mb = blockIdx.y * 128, nb = blockIdx.x * 128;
    int tid = threadIdx.x;
    int w = tid >> 6, lane = tid & 63, lo = lane & 15, qu = lane >> 4;
    int wm = (w >> 1) * 64, wn = (w & 1) * 64;
    int srow_in_wave = lane >> 2;
    int schunk = lane & 3;
    f32x4 zero = {0.f, 0.f, 0.f, 0.f};
    f32x4 acc[4][4];
#pragma unroll
    for (int i = 0; i < 4; i++)
#pragma unroll
        for (int j = 0; j < 4; j++) acc[i][j] = zero;

    int fswz = (lo >> 1) & 3;

    for (int kb = 0; kb < K; kb += 32) {
        __syncthreads();
#pragma unroll
        for (int u = 0; u < 2; u++) {
            int row0 = w * 32 + u * 16;
            int row = row0 + srow_in_wave;
            int cg = schunk ^ ((row >> 1) & 3);
            GLOAD_LDS16(A + (size_t)(mb + row) * K + kb + cg * 8, &Asm[row0 * 32]);
            GLOAD_LDS16(BT + (size_t)(nb + row) * K + kb + cg * 8, &Bsm[row0 * 32]);
        }
        __syncthreads();
        bf16x8 af[4], bfr[4];
#pragma unroll
        for (int t = 0; t < 4; t++) {
            af[t]  = *reinterpret_cast<const bf16x8*>(
                &Asm[(wm + t * 16 + lo) * 32 + (qu ^ fswz) * 8]);
            bfr[t] = *reinterpret_cast<const bf16x8*>(
                &Bsm[(wn + t * 16 + lo) * 32 + (qu ^ fswz) * 8]);
        }
#pragma unroll
        for (int i = 0; i < 4; i++)
#pragma unroll
            for (int j = 0; j < 4; j++)
                acc[i][j] = __builtin_amdgcn_mfma_f32_16x16x32_bf16(af[i], bfr[j],
                                                                    acc[i][j], 0, 0, 0);
    }
#pragma unroll
    for (int i = 0; i < 4; i++) {
#pragma unroll
        for (int j = 0; j < 4; j++) {
            int col = nb + wn + j * 16 + lo;
            float bv = bias[col];
            float v4v[4];
#pragma unroll
            for (int r = 0; r < 4; r++) v4v[r] = acc[i][j][r] + bv;
            int row0 = mb + wm + i * 16 + qu * 4;
            if (MODE == 0) {
                int b = row0 >> 11, s0 = row0 & 2047;
                int which = col >> 10, rem = col & 1023;
                int h = rem >> 6, d = rem & 63;
                int bh = b * H_ + h;
                if (which == 2) {
                    bf16x4 pk;
#pragma unroll
                    for (int r = 0; r < 4; r++) pk[r] = (bf16)v4v[r];
                    *reinterpret_cast<bf16x4*>(
                        (bf16*)out2 + ((size_t)bh * HD_ + d) * S_ + s0) = pk;
                } else {
                    bf16* dst = which == 0 ? (bf16*)out0 : (bf16*)out1;
                    float sc = which == 0 ? QSCALE : 1.0f;
#pragma unroll
                    for (int r = 0; r < 4; r++)
                        dst[((size_t)bh * S_ + s0 + r) * HD_ + d] = (bf16)(v4v[r] * sc);
                }
            } else {
#pragma unroll
                for (int r = 0; r < 4; r++)
                    ((float*)out0)[(size_t)(row0 + r) * N + col] = v4v[r];
            }
        }
    }
}

// ---------------- flash attention v7: barrier-free, balanced ----------------
// grid 1024 x 256; wave = one (bh, 32q chunk). No __syncthreads.
// Q prescaled by 0.125*log2e; p = exp2(score) fixed-max (softmax-exact fp32).
// K frags from K[bh][s][d]; V frags from Vt[bh][d][s]; all L2-resident.
// q-chunk mapping balanced so each CU's 4 blocks sum to equal work.
__global__ __launch_bounds__(256) void k_attn(
    const bf16* __restrict__ Q, const bf16* __restrict__ K,
    const bf16* __restrict__ Vt, bf16* __restrict__ Y) {
    __shared__ __align__(16) bf16 Psm[4][32][72];  // per-wave [q][key]
    int blk = blockIdx.x;
    int g = blk & 15, jp = blk >> 4;   // jp 0..63
    int tid = threadIdx.x, w = tid >> 6, lane = tid & 63;
    int lo = lane & 15, qu = lane >> 4;
    int bh = g * 4 + w;
    // balanced mapping: u=0: j=q | u=1: 63-q | u=2: 16+q | u=3: 47-q
    int u = jp >> 4, qq = jp & 15;
    int j = (u == 0) ? qq : (u == 1) ? 63 - qq : (u == 2) ? 16 + qq : 47 - qq;
    int qbase = j * 32;
    int b = bh >> 4, h = bh & 15;
    const bf16* Qb = Q + (size_t)bh * S_ * HD_;
    const bf16* Kb = K + (size_t)bh * S_ * HD_;
    const bf16* Vb = Vt + (size_t)bh * HD_ * S_;

    // Q fragments (A layout: m=lo, k=qu*8+jj, +32*ks)
    bf16x8 qf[2][2];
#pragma unroll
    for (int i = 0; i < 2; i++)
#pragma unroll
        for (int ks = 0; ks < 2; ks++)
            qf[i][ks] = *reinterpret_cast<const bf16x8*>(
                Qb + (size_t)(qbase + i * 16 + lo) * HD_ + ks * 32 + qu * 8);

    f32x4 zero = {0.f, 0.f, 0.f, 0.f};
    f32x4 o[2][4];
    float l_i[2][4];
#pragma unroll
    for (int i = 0; i < 2; i++)
#pragma unroll
        for (int r = 0; r < 4; r++) { o[i][r] = zero; l_i[i][r] = 0.f; }

    int nt = (qbase + 95) >> 6;
    for (int t = 0; t < nt; t++) {
        int kb = t * 64;
        // ---- K fragments straight from global (B layout: n=key, k=d) ----
        bf16x8 kf[4][2];
#pragma unroll
        for (int kc = 0; kc < 4; kc++) {
            const bf16* kp = Kb + (size_t)(kb + kc * 16 + lo) * HD_ + qu * 8;
            kf[kc][0] = *reinterpret_cast<const bf16x8*>(kp);
            kf[kc][1] = *reinterpret_cast<const bf16x8*>(kp + 32);
        }
        // ---- S = Q K^T ----
        f32x4 sc[2][4];
#pragma unroll
        for (int kc = 0; kc < 4; kc++)
#pragma unroll
            for (int i = 0; i < 2; i++) {
                f32x4 a = __builtin_amdgcn_mfma_f32_16x16x32_bf16(qf[i][0], kf[kc][0], zero, 0, 0, 0);
                sc[i][kc] = __builtin_amdgcn_mfma_f32_16x16x32_bf16(qf[i][1], kf[kc][1], a, 0, 0, 0);
            }
        // ---- mask (diagonal tiles only) + exp2 + row-sum ----
        if (kb + 63 > qbase) {
#pragma unroll
            for (int kc = 0; kc < 4; kc++) {
                int kj = kb + kc * 16 + lo;
#pragma unroll
                for (int i = 0; i < 2; i++) {
                    int qi = qbase + i * 16 + qu * 4;
#pragma unroll
                    for (int r = 0; r < 4; r++)
                        sc[i][kc][r] = (kj > qi + r) ? -1e30f : sc[i][kc][r];
                }
            }
        }
#pragma unroll
        for (int i = 0; i < 2; i++)
#pragma unroll
            for (int kc = 0; kc < 4; kc++)
#pragma unroll
                for (int r = 0; r < 4; r++)
                    sc[i][kc][r] = EXP2F(sc[i][kc][r]);
#pragma unroll
        for (int i = 0; i < 2; i++)
#pragma unroll
            for (int r = 0; r < 4; r++) {
                float s = (sc[i][0][r] + sc[i][1][r]) + (sc[i][2][r] + sc[i][3][r]);
                l_i[i][r] += rowsum16(s);
            }
        // ---- P: C layout -> per-wave LDS -> A layout ----
#pragma unroll
        for (int i = 0; i < 2; i++)
#pragma unroll
            for (int kc = 0; kc < 4; kc++)
#pragma unroll
                for (int r = 0; r < 4; r++)
                    Psm[w][i * 16 + qu * 4 + r][kc * 16 + lo] = (bf16)sc[i][kc][r];
        // ---- V fragments from global (issued before the lgkm wait) ----
        bf16x8 vf[4][2];
#pragma unroll
        for (int nc = 0; nc < 4; nc++) {
            const bf16* vp = Vb + (size_t)(nc * 16 + lo) * S_ + kb + qu * 8;
            vf[nc][0] = *reinterpret_cast<const bf16x8*>(vp);
            vf[nc][1] = *reinterpret_cast<const bf16x8*>(vp + 32);
        }
        asm volatile("s_waitcnt lgkmcnt(0)" ::: "memory");
        bf16x8 pa[2][2];
#pragma unroll
        for (int i = 0; i < 2; i++)
#pragma unroll
            for (int ks = 0; ks < 2; ks++)
                pa[i][ks] = *reinterpret_cast<const bf16x8*>(
                    &Psm[w][i * 16 + lo][ks * 32 + qu * 8]);
        // ---- O += P V ----
#pragma unroll
        for (int nc = 0; nc < 4; nc++)
#pragma unroll
            for (int i = 0; i < 2; i++) {
                o[i][nc] = __builtin_amdgcn_mfma_f32_16x16x32_bf16(pa[i][0], vf[nc][0], o[i][nc], 0, 0, 0);
                o[i][nc] = __builtin_amdgcn_mfma_f32_16x16x32_bf16(pa[i][1], vf[nc][1], o[i][nc], 0, 0, 0);
            }
    }
    // epilogue: Y[b, s, h*64 + d] bf16  (l_i uniform across the 16-lane row)
#pragma unroll
    for (int i = 0; i < 2; i++) {
#pragma unroll
        for (int r = 0; r < 4; r++) {
            float inv = RCPF(l_i[i][r]);
            int s = qbase + i * 16 + qu * 4 + r;
#pragma unroll
            for (int nc = 0; nc < 4; nc++) {
                float v = o[i][nc][r] * inv;
                Y[((size_t)(b * S_ + s) * H_ + h) * HD_ + nc * 16 + lo] = (bf16)v;
            }
        }
    }
}

extern "C" void kernel_launch(void* const* d_in, const int* in_sizes, int n_in,
                              void* d_out, int out_size, void* d_ws, size_t ws_size,
                              hipStream_t stream) {
    const float* x      = (const float*)d_in[0];
    const float* W_attn = (const float*)d_in[1];
    const float* b_attn = (const float*)d_in[2];
    const float* W_proj = (const float*)d_in[3];
    const float* b_proj = (const float*)d_in[4];
    float* out = (float*)d_out;

    char* ws = (char*)d_ws;
    size_t off = 0;
    auto alloc = [&](size_t bytes) -> void* {
        void* p = ws + off;
        off += (bytes + 255) & ~(size_t)255;
        return p;
    };
    const size_t MD = (size_t)B_ * S_ * D_;  // 8388608
    bf16* xb  = (bf16*)alloc(MD * 2);
    bf16* wta = (bf16*)alloc((size_t)3 * D_ * D_ * 2);
    bf16* wtp = (bf16*)alloc((size_t)D_ * D_ * 2);
    bf16* Qb  = (bf16*)alloc(MD * 2);
    bf16* Kb  = (bf16*)alloc(MD * 2);
    bf16* Vtb = (bf16*)alloc(MD * 2);  // V written transposed by GEMM1
    bf16* Ya  = (bf16*)alloc(MD * 2);

    k_cvt<<<8192, 256, 0, stream>>>(x, xb, (int)MD);
    k_transpose_cvt<<<dim3(96, 32), 256, 0, stream>>>(W_attn, wta, D_, 3 * D_);
    k_transpose_cvt<<<dim3(32, 32), 256, 0, stream>>>(W_proj, wtp, D_, D_);
    k_gemm<0><<<dim3(24, 64), 256, 0, stream>>>(xb, wta, b_attn, Qb, Kb, Vtb,
                                                B_ * S_, 3 * D_, D_);
    k_attn<<<dim3(1024), 256, 0, stream>>>(Qb, Kb, Vtb, Ya);
    k_gemm<1><<<dim3(8, 64), 256, 0, stream>>>(Ya, wtp, b_proj, out, nullptr, nullptr,
                                               B_ * S_, D_, D_);
}